// Round 7
// baseline (142.542 us; speedup 1.0000x reference)
//
#include <hip/hip_runtime.h>
#include <math.h>

// MultiHeadAttention_3728031613617 — bf16-MFMA pipeline v7.
// v7 = v6 with ONE change: flash Q-tile 16 -> 32 at CONSTANT occupancy
// (block 512 = 8 waves, wave-private 8KB slots, P aliases K slot, Q frags
// in registers) — halves the L2 K/V re-read traffic (536 -> ~270 MB), the
// dominant term in flash's roofline, and doubles MFMA per staged byte.
// prep/proj/out_gemm verbatim from v6 (measured fine).

typedef __bf16 bf16;
typedef __bf16 bf16x4v __attribute__((ext_vector_type(4)));
typedef __bf16 bf16x8v __attribute__((ext_vector_type(8)));
typedef float f32x4 __attribute__((ext_vector_type(4)));

namespace {
constexpr int kS = 2048;
constexpr int kD = 512;
constexpr int kH = 64;
constexpr int kRows = 16384;  // 8 * 2048
}

#define MFMA16(a, b, c) __builtin_amdgcn_mfma_f32_16x16x32_bf16((a), (b), (c), 0, 0, 0)

// ---------------------------------------------------------------------------
// Kernel 0: prep. wtg[mat][n=64][k=512] = (bf16)W[mat][k][n]
//           dr[j=64][o=512] = (f32) sum_h dense[h*64+j, o]
// ---------------------------------------------------------------------------
__global__ __launch_bounds__(256) void prep_kernel(const float* __restrict__ w,
                                                   const float* __restrict__ dense,
                                                   bf16* __restrict__ wtg,
                                                   float* __restrict__ dr) {
  int idx = blockIdx.x * 256 + threadIdx.x;  // < 131072
  if (idx < 98304) {
    int mat = idx >> 15, rem = idx & 32767;
    int n = rem >> 9, k = rem & 511;
    wtg[idx] = (bf16)w[mat * 32768 + k * 64 + n];
  } else {
    int e = idx - 98304;  // < 32768
    int j = e >> 9, o = e & 511;
    float s = 0.f;
#pragma unroll
    for (int h = 0; h < 8; ++h) s += dense[(size_t)(h * 64 + j) * kD + o];
    dr[e] = s;  // [j][o] f32
  }
}

// ---------------------------------------------------------------------------
// Kernel 1: fused QKV projection (x read ONCE). grid 256, block 256. (v6)
// ---------------------------------------------------------------------------
__global__ __launch_bounds__(256) void proj_kernel(const float* __restrict__ x,
                                                   const bf16* __restrict__ wtg,
                                                   bf16* __restrict__ wq,
                                                   bf16* __restrict__ wk,
                                                   bf16* __restrict__ wvt) {
  const int bt = blockIdx.x;
  const int tid = threadIdx.x;
  const int w = tid >> 6, tx = tid & 15, quad = (tid >> 4) & 3;
  const int row0 = bt * 64;

  __shared__ bf16 Xs[64 * 72];
  __shared__ bf16 Wts[3 * 64 * 72];

  f32x4 acc[3][4];
#pragma unroll
  for (int m = 0; m < 3; ++m)
#pragma unroll
    for (int nt = 0; nt < 4; ++nt) acc[m][nt] = (f32x4){0.f, 0.f, 0.f, 0.f};

  for (int k0 = 0; k0 < kD; k0 += 64) {
    __syncthreads();
#pragma unroll
    for (int p = 0; p < 4; ++p) {
      int i4 = tid + p * 256;
      int r = i4 >> 4, c4 = (i4 & 15) * 4;
      float4 f = *(const float4*)&x[(size_t)(row0 + r) * kD + k0 + c4];
      bf16x4v h = {(bf16)f.x, (bf16)f.y, (bf16)f.z, (bf16)f.w};
      *(bf16x4v*)&Xs[r * 72 + c4] = h;
    }
#pragma unroll
    for (int p = 0; p < 6; ++p) {
      int cc = tid + p * 256;
      int mat = cc >> 9, rem = cc & 511;
      int n = rem >> 3, c8 = (rem & 7) * 8;
      *(uint4*)&Wts[(mat * 64 + n) * 72 + c8] =
          *(const uint4*)&wtg[(size_t)mat * 32768 + (size_t)n * 512 + k0 + c8];
    }
    __syncthreads();
#pragma unroll
    for (int s = 0; s < 2; ++s) {
      bf16x8v a = *(bf16x8v*)&Xs[(w * 16 + tx) * 72 + s * 32 + quad * 8];
#pragma unroll
      for (int m = 0; m < 3; ++m)
#pragma unroll
        for (int nt = 0; nt < 4; ++nt) {
          bf16x8v bfr =
              *(bf16x8v*)&Wts[(m * 64 + nt * 16 + tx) * 72 + s * 32 + quad * 8];
          acc[m][nt] = MFMA16(a, bfr, acc[m][nt]);
        }
    }
  }

#pragma unroll
  for (int nt = 0; nt < 4; ++nt)
#pragma unroll
    for (int r = 0; r < 4; ++r) {
      int row_g = row0 + w * 16 + quad * 4 + r;
      int col = nt * 16 + tx;
      wq[(size_t)row_g * 64 + col] = (bf16)acc[0][nt][r];
      wk[(size_t)row_g * 64 + col] = (bf16)acc[1][nt][r];
    }
  __syncthreads();
  bf16* Vt = Xs;
#pragma unroll
  for (int nt = 0; nt < 4; ++nt)
#pragma unroll
    for (int r = 0; r < 4; ++r)
      Vt[(nt * 16 + tx) * 72 + (w * 16 + quad * 4 + r)] = (bf16)acc[2][nt][r];
  __syncthreads();
#pragma unroll
  for (int p = 0; p < 2; ++p) {
    int c = tid + p * 256;
    int v = c >> 3, seg = c & 7;
    *(uint4*)&wvt[(size_t)v * kRows + row0 + seg * 8] =
        *(uint4*)&Vt[v * 72 + seg * 8];
  }
}

// ---------------------------------------------------------------------------
// Kernel 2: flash attention v7 — Q-tile 32, block 512 (8 waves), grid 512.
// b = bid&7 (XCD affinity), qb = bid>>3 (32 Q-rows). Wave w owns key tiles
// (t*8+w)*32, t<8. Barrier-free main loop, wave-private 8KB LDS slots
// (K 4KB [P aliases first 2KB], V 4KB), XOR chunk swizzle (r5-verified).
// Q fragments register-resident (loop-invariant global load).
// LDS 66560 B -> 2 blocks/CU = 16 waves/CU (same as v6).
// ---------------------------------------------------------------------------
__global__ __launch_bounds__(512, 4) void flash_kernel(
    const bf16* __restrict__ wq, const bf16* __restrict__ wk,
    const bf16* __restrict__ wvt, float* __restrict__ vo) {
  const int bid = blockIdx.x;
  const int b = bid & 7, qb = bid >> 3;
  const int q0 = qb * 32;
  const int tid = threadIdx.x;
  const int w = tid >> 6, lane = tid & 63, tx = tid & 15, quad = (tid >> 4) & 3;

  __shared__ __align__(16) char lds[65536];  // 8 waves x 8KB slots
  __shared__ float Lsh[256];                 // 8 waves x 32 rows
  bf16* Ksw = (bf16*)(lds + w * 8192);        // 32 keys x 64 c (swizzled)
  bf16* Psw = Ksw;                            // 32 q x 32 k, aliases K[0:16]
  bf16* Vtw = (bf16*)(lds + w * 8192 + 4096); // 64 v x 32 keys (swizzled)

  const bf16* wqb = wq + (size_t)(b * kS) * 64;
  const bf16* wkb = wk + (size_t)(b * kS) * 64;
  const bf16* wvb = wvt + b * kS;

  const int kc0 = (quad ^ (tx & 7)) * 8;        // 64-wide rows, s=0 chunk
  const int kc1 = ((4 + quad) ^ (tx & 7)) * 8;  // s=1 chunk
  const int h2 = (tx ^ (tx >> 2)) & 3;          // 32-wide rows keyed by tx

  // Q fragments: loop-invariant, direct from global (one-time cost)
  bf16x8v aq[2][2];
#pragma unroll
  for (int rt = 0; rt < 2; ++rt)
#pragma unroll
    for (int s = 0; s < 2; ++s)
      aq[rt][s] = *(const bf16x8v*)&wqb[(size_t)(q0 + rt * 16 + tx) * 64 +
                                        s * 32 + quad * 8];

  f32x4 oacc[2][4];
#pragma unroll
  for (int rt = 0; rt < 2; ++rt)
#pragma unroll
    for (int nt = 0; nt < 4; ++nt) oacc[rt][nt] = (f32x4){0.f, 0.f, 0.f, 0.f};
  float lsum[2][4] = {};

  const int ksr = lane >> 3, kslc = lane & 7;  // K staging: 8 lanes/row
  const int vsv = lane >> 2, vsck = lane & 3;  // V staging: 4 lanes/v-row

  for (int t = 0; t < 8; ++t) {
    const int k0 = (t * 8 + w) * 32;
    // direct global->LDS staging (v6 form; compiler batches the loads)
#pragma unroll
    for (int j = 0; j < 4; ++j) {
      int r = ksr + j * 8;
      *(uint4*)&Ksw[r * 64 + ((kslc ^ (r & 7)) * 8)] =
          *(const uint4*)&wkb[(size_t)(k0 + r) * 64 + kslc * 8];
      int v = vsv + j * 16;
      *(uint4*)&Vtw[v * 32 + ((vsck ^ ((v ^ (v >> 2)) & 3)) * 8)] =
          *(const uint4*)&wvb[(size_t)v * kRows + k0 + vsck * 8];
    }

    // QK^T: D[32 q][32 keys]; P store aliases K rows 0..15 (disjoint from
    // nt=1's K reads at rows 16..31; LDS ops are in-order per wave).
#pragma unroll
    for (int nt = 0; nt < 2; ++nt) {
      int krow = nt * 16 + tx;
      bf16x8v b0 = *(bf16x8v*)&Ksw[krow * 64 + kc0];
      bf16x8v b1 = *(bf16x8v*)&Ksw[krow * 64 + kc1];
#pragma unroll
      for (int rt = 0; rt < 2; ++rt) {
        f32x4 z = (f32x4){0.f, 0.f, 0.f, 0.f};
        z = MFMA16(aq[rt][0], b0, z);
        z = MFMA16(aq[rt][1], b1, z);
        // no-max softmax numerator + swizzled P store (C -> A layout)
#pragma unroll
        for (int r = 0; r < 4; ++r) {
          float p = __expf(z[r] * 0.1f);
          lsum[rt][r] += p;
          int q = rt * 16 + quad * 4 + r;
          int chunk = nt * 2 + (tx >> 3);
          Psw[q * 32 + ((chunk ^ (r ^ quad)) * 8) + (tx & 7)] = (bf16)p;
        }
      }
    }

    // PV: O[32 q][64 v] += P[32][32] * V[32][64]
#pragma unroll
    for (int rt = 0; rt < 2; ++rt) {
      bf16x8v pa = *(bf16x8v*)&Psw[(rt * 16 + tx) * 32 + ((quad ^ h2) * 8)];
#pragma unroll
      for (int nt = 0; nt < 4; ++nt) {
        bf16x8v vb = *(bf16x8v*)&Vtw[(nt * 16 + tx) * 32 + ((quad ^ h2) * 8)];
        oacc[rt][nt] = MFMA16(pa, vb, oacc[rt][nt]);
      }
    }
  }

  // ---- cross-wave combine (private 8KB f32 regions, no atomics) ----
  __syncthreads();
  float* myO = (float*)(lds + w * 8192);  // 32 x 64 f32 (exactly 8KB)
  float* myL = Lsh + w * 32;
#pragma unroll
  for (int rt = 0; rt < 2; ++rt)
#pragma unroll
    for (int nt = 0; nt < 4; ++nt)
#pragma unroll
      for (int r = 0; r < 4; ++r)
        myO[(rt * 16 + quad * 4 + r) * 64 + nt * 16 + tx] = oacc[rt][nt][r];
#pragma unroll
  for (int rt = 0; rt < 2; ++rt)
#pragma unroll
    for (int r = 0; r < 4; ++r) {
      float v = lsum[rt][r];
#pragma unroll
      for (int m = 1; m < 16; m <<= 1) v += __shfl_xor(v, m, 64);
      if (tx == 0) myL[rt * 16 + quad * 4 + r] = v;
    }
  __syncthreads();

#pragma unroll
  for (int p = 0; p < 4; ++p) {
    int e = tid + p * 512;  // 2048: 32 rows x 64 cols
    int row = e >> 6;
    float s = 0.f, lt = 0.f;
#pragma unroll
    for (int wv = 0; wv < 8; ++wv) {
      s += ((const float*)(lds + wv * 8192))[e];
      lt += Lsh[wv * 32 + row];
    }
    vo[(size_t)(b * kS + q0 + row) * 64 + (e & 63)] = s / lt;
  }
}

// ---------------------------------------------------------------------------
// Kernel 3: out = vo [16384,64] @ dr [64,512], fp32 (v6, validated).
// ---------------------------------------------------------------------------
__global__ __launch_bounds__(256) void out_gemm_kernel(
    const float* __restrict__ v, const float* __restrict__ dr,
    float* __restrict__ out) {
  const int rt = blockIdx.x, ct = blockIdx.y;
  const int tid = threadIdx.x;
  const int tx = tid & 15, ty = tid >> 4;

  __shared__ float As[64][68];
  __shared__ float Bs[64][68];

#pragma unroll
  for (int p = 0; p < 4; ++p) {
    int f4 = tid + p * 256;
    int r = f4 >> 4, c = (f4 & 15) * 4;
    *(float4*)&As[r][c] = *(const float4*)(v + (size_t)(rt * 64 + r) * kH + c);
    *(float4*)&Bs[r][c] = *(const float4*)(dr + (size_t)r * kD + ct * 64 + c);
  }
  __syncthreads();

  float acc[4][4] = {};
#pragma unroll
  for (int k = 0; k < 64; k += 4) {
    float a[4][4], bb[4][4];
#pragma unroll
    for (int i = 0; i < 4; ++i) {
      float4 t = *(const float4*)&As[ty * 4 + i][k];
      a[i][0] = t.x; a[i][1] = t.y; a[i][2] = t.z; a[i][3] = t.w;
    }
#pragma unroll
    for (int kk = 0; kk < 4; ++kk) {
      float4 t = *(const float4*)&Bs[k + kk][tx * 4];
      bb[kk][0] = t.x; bb[kk][1] = t.y; bb[kk][2] = t.z; bb[kk][3] = t.w;
    }
#pragma unroll
    for (int i = 0; i < 4; ++i)
#pragma unroll
      for (int kk = 0; kk < 4; ++kk)
#pragma unroll
        for (int j = 0; j < 4; ++j)
          acc[i][j] = fmaf(a[i][kk], bb[kk][j], acc[i][j]);
  }
#pragma unroll
  for (int i = 0; i < 4; ++i) {
    float4 vv = make_float4(acc[i][0], acc[i][1], acc[i][2], acc[i][3]);
    *(float4*)(out + (size_t)(rt * 64 + ty * 4 + i) * kD + ct * 64 + tx * 4) = vv;
  }
}

extern "C" void kernel_launch(void* const* d_in, const int* in_sizes, int n_in,
                              void* d_out, int out_size, void* d_ws,
                              size_t ws_size, hipStream_t stream) {
  const float* x = (const float*)d_in[0];      // [8,2048,512]
  const float* w = (const float*)d_in[1];      // [3,512,64]
  const float* dense = (const float*)d_in[2];  // [512,512]
  float* out = (float*)d_out;                  // [8,2048,512] fp32

  bf16* wq = (bf16*)d_ws;                // 1,048,576 bf16
  bf16* wk = wq + (size_t)kRows * 64;    // 1,048,576
  bf16* wvt = wk + (size_t)kRows * 64;   // 1,048,576  [64][16384]
  bf16* wtg = wvt + (size_t)kRows * 64;  // 98,304     [3][64][512]
  float* dr = (float*)(wtg + 98304);     // 32,768 f32 [64][512]
  float* vo = dr + 32768;                // 1,048,576 f32

  prep_kernel<<<512, 256, 0, stream>>>(w, dense, wtg, dr);
  proj_kernel<<<256, 256, 0, stream>>>(x, wtg, wq, wk, wvt);
  flash_kernel<<<512, 512, 0, stream>>>(wq, wk, wvt, vo);
  out_gemm_kernel<<<dim3(kRows / 64, kD / 64), 256, 0, stream>>>(vo, dr, out);
}

// Round 8
// 138.316 us; speedup vs baseline: 1.0306x; 1.0306x over previous
//
#include <hip/hip_runtime.h>
#include <math.h>

// MultiHeadAttention_3728031613617 — bf16-MFMA pipeline v8.
// v8 = v7 with the dense GEMM fused into flash's tail, writing `out`
// directly with COALESCED full-row float4 stores via an LDS-staged
// transpose (fixes r4's 3.3x write amplification, the fused epilogue's
// one counter-documented defect). out_gemm + vo round-trip removed.
// Main loop / combine verbatim from v7 (measured = v6's plateau).

typedef __bf16 bf16;
typedef __bf16 bf16x4v __attribute__((ext_vector_type(4)));
typedef __bf16 bf16x8v __attribute__((ext_vector_type(8)));
typedef float f32x4 __attribute__((ext_vector_type(4)));

namespace {
constexpr int kS = 2048;
constexpr int kD = 512;
constexpr int kRows = 16384;  // 8 * 2048
}

#define MFMA16(a, b, c) __builtin_amdgcn_mfma_f32_16x16x32_bf16((a), (b), (c), 0, 0, 0)

// ---------------------------------------------------------------------------
// Kernel 0: prep. wtg[mat][n=64][k=512] = (bf16)W[mat][k][n]
//           drt[o=512][j=64] = (bf16) sum_h dense[h*64+j, o]  (for B-frags)
// ---------------------------------------------------------------------------
__global__ __launch_bounds__(256) void prep_kernel(const float* __restrict__ w,
                                                   const float* __restrict__ dense,
                                                   bf16* __restrict__ wtg,
                                                   bf16* __restrict__ drt) {
  int idx = blockIdx.x * 256 + threadIdx.x;  // < 131072
  if (idx < 98304) {
    int mat = idx >> 15, rem = idx & 32767;
    int n = rem >> 9, k = rem & 511;
    wtg[idx] = (bf16)w[mat * 32768 + k * 64 + n];
  } else {
    int e = idx - 98304;  // < 32768
    int o = e >> 6, j = e & 63;
    float s = 0.f;
#pragma unroll
    for (int h = 0; h < 8; ++h) s += dense[(size_t)(h * 64 + j) * kD + o];
    drt[e] = (bf16)s;  // [o][j]
  }
}

// ---------------------------------------------------------------------------
// Kernel 1: fused QKV projection (x read ONCE). grid 256, block 256. (v6)
// ---------------------------------------------------------------------------
__global__ __launch_bounds__(256) void proj_kernel(const float* __restrict__ x,
                                                   const bf16* __restrict__ wtg,
                                                   bf16* __restrict__ wq,
                                                   bf16* __restrict__ wk,
                                                   bf16* __restrict__ wvt) {
  const int bt = blockIdx.x;
  const int tid = threadIdx.x;
  const int w = tid >> 6, tx = tid & 15, quad = (tid >> 4) & 3;
  const int row0 = bt * 64;

  __shared__ bf16 Xs[64 * 72];
  __shared__ bf16 Wts[3 * 64 * 72];

  f32x4 acc[3][4];
#pragma unroll
  for (int m = 0; m < 3; ++m)
#pragma unroll
    for (int nt = 0; nt < 4; ++nt) acc[m][nt] = (f32x4){0.f, 0.f, 0.f, 0.f};

  for (int k0 = 0; k0 < kD; k0 += 64) {
    __syncthreads();
#pragma unroll
    for (int p = 0; p < 4; ++p) {
      int i4 = tid + p * 256;
      int r = i4 >> 4, c4 = (i4 & 15) * 4;
      float4 f = *(const float4*)&x[(size_t)(row0 + r) * kD + k0 + c4];
      bf16x4v h = {(bf16)f.x, (bf16)f.y, (bf16)f.z, (bf16)f.w};
      *(bf16x4v*)&Xs[r * 72 + c4] = h;
    }
#pragma unroll
    for (int p = 0; p < 6; ++p) {
      int cc = tid + p * 256;
      int mat = cc >> 9, rem = cc & 511;
      int n = rem >> 3, c8 = (rem & 7) * 8;
      *(uint4*)&Wts[(mat * 64 + n) * 72 + c8] =
          *(const uint4*)&wtg[(size_t)mat * 32768 + (size_t)n * 512 + k0 + c8];
    }
    __syncthreads();
#pragma unroll
    for (int s = 0; s < 2; ++s) {
      bf16x8v a = *(bf16x8v*)&Xs[(w * 16 + tx) * 72 + s * 32 + quad * 8];
#pragma unroll
      for (int m = 0; m < 3; ++m)
#pragma unroll
        for (int nt = 0; nt < 4; ++nt) {
          bf16x8v bfr =
              *(bf16x8v*)&Wts[(m * 64 + nt * 16 + tx) * 72 + s * 32 + quad * 8];
          acc[m][nt] = MFMA16(a, bfr, acc[m][nt]);
        }
    }
  }

#pragma unroll
  for (int nt = 0; nt < 4; ++nt)
#pragma unroll
    for (int r = 0; r < 4; ++r) {
      int row_g = row0 + w * 16 + quad * 4 + r;
      int col = nt * 16 + tx;
      wq[(size_t)row_g * 64 + col] = (bf16)acc[0][nt][r];
      wk[(size_t)row_g * 64 + col] = (bf16)acc[1][nt][r];
    }
  __syncthreads();
  bf16* Vt = Xs;
#pragma unroll
  for (int nt = 0; nt < 4; ++nt)
#pragma unroll
    for (int r = 0; r < 4; ++r)
      Vt[(nt * 16 + tx) * 72 + (w * 16 + quad * 4 + r)] = (bf16)acc[2][nt][r];
  __syncthreads();
#pragma unroll
  for (int p = 0; p < 2; ++p) {
    int c = tid + p * 256;
    int v = c >> 3, seg = c & 7;
    *(uint4*)&wvt[(size_t)v * kRows + row0 + seg * 8] =
        *(uint4*)&Vt[v * 72 + seg * 8];
  }
}

// ---------------------------------------------------------------------------
// Kernel 2: flash attention v8 — v7 main loop + fused coalesced dense tail.
// grid 512: b = bid&7, qb = bid>>3 (32 Q-rows). Block 512 = 8 waves; wave w
// owns key tiles (t*8+w)*32, t<8. Barrier-free main loop, wave-private 8KB
// slots (P aliases K), XOR swizzle. Tail: combine -> vob bf16 -> dense MFMA
// vs drt -> LDS-staged 32x256 f32 chunks -> full-row float4 stores to out.
// LDS: 64KB slots (reused as OutS) + 1KB Lsh + 4KB vob = 70656 B -> 2 blk/CU.
// ---------------------------------------------------------------------------
__global__ __launch_bounds__(512, 4) void flash_kernel(
    const bf16* __restrict__ wq, const bf16* __restrict__ wk,
    const bf16* __restrict__ wvt, const bf16* __restrict__ drt,
    float* __restrict__ out) {
  const int bid = blockIdx.x;
  const int b = bid & 7, qb = bid >> 3;
  const int q0 = qb * 32;
  const int tid = threadIdx.x;
  const int w = tid >> 6, lane = tid & 63, tx = tid & 15, quad = (tid >> 4) & 3;

  __shared__ __align__(16) char lds[65536];   // 8 waves x 8KB slots
  __shared__ float Lsh[256];                  // 8 waves x 32 rows
  __shared__ __align__(16) bf16 vob[32 * 64]; // combined O, swizzled rows
  bf16* Ksw = (bf16*)(lds + w * 8192);        // 32 keys x 64 c (swizzled)
  bf16* Psw = Ksw;                            // 32 q x 32 k, aliases K[0:16]
  bf16* Vtw = (bf16*)(lds + w * 8192 + 4096); // 64 v x 32 keys (swizzled)

  const bf16* wqb = wq + (size_t)(b * kS) * 64;
  const bf16* wkb = wk + (size_t)(b * kS) * 64;
  const bf16* wvb = wvt + b * kS;

  const int kc0 = (quad ^ (tx & 7)) * 8;        // 64-wide rows, s=0 chunk
  const int kc1 = ((4 + quad) ^ (tx & 7)) * 8;  // s=1 chunk
  const int h2 = (tx ^ (tx >> 2)) & 3;          // 32-wide rows keyed by tx

  // Q fragments: loop-invariant, direct from global (one-time cost)
  bf16x8v aq[2][2];
#pragma unroll
  for (int rt = 0; rt < 2; ++rt)
#pragma unroll
    for (int s = 0; s < 2; ++s)
      aq[rt][s] = *(const bf16x8v*)&wqb[(size_t)(q0 + rt * 16 + tx) * 64 +
                                        s * 32 + quad * 8];

  f32x4 oacc[2][4];
#pragma unroll
  for (int rt = 0; rt < 2; ++rt)
#pragma unroll
    for (int nt = 0; nt < 4; ++nt) oacc[rt][nt] = (f32x4){0.f, 0.f, 0.f, 0.f};
  float lsum[2][4] = {};

  const int ksr = lane >> 3, kslc = lane & 7;  // K staging: 8 lanes/row
  const int vsv = lane >> 2, vsck = lane & 3;  // V staging: 4 lanes/v-row

  for (int t = 0; t < 8; ++t) {
    const int k0 = (t * 8 + w) * 32;
#pragma unroll
    for (int j = 0; j < 4; ++j) {
      int r = ksr + j * 8;
      *(uint4*)&Ksw[r * 64 + ((kslc ^ (r & 7)) * 8)] =
          *(const uint4*)&wkb[(size_t)(k0 + r) * 64 + kslc * 8];
      int v = vsv + j * 16;
      *(uint4*)&Vtw[v * 32 + ((vsck ^ ((v ^ (v >> 2)) & 3)) * 8)] =
          *(const uint4*)&wvb[(size_t)v * kRows + k0 + vsck * 8];
    }

    // QK^T + no-max softmax numerator + swizzled P store (C -> A layout)
#pragma unroll
    for (int nt = 0; nt < 2; ++nt) {
      int krow = nt * 16 + tx;
      bf16x8v b0 = *(bf16x8v*)&Ksw[krow * 64 + kc0];
      bf16x8v b1 = *(bf16x8v*)&Ksw[krow * 64 + kc1];
#pragma unroll
      for (int rt = 0; rt < 2; ++rt) {
        f32x4 z = (f32x4){0.f, 0.f, 0.f, 0.f};
        z = MFMA16(aq[rt][0], b0, z);
        z = MFMA16(aq[rt][1], b1, z);
#pragma unroll
        for (int r = 0; r < 4; ++r) {
          float p = __expf(z[r] * 0.1f);
          lsum[rt][r] += p;
          int q = rt * 16 + quad * 4 + r;
          int chunk = nt * 2 + (tx >> 3);
          Psw[q * 32 + ((chunk ^ (r ^ quad)) * 8) + (tx & 7)] = (bf16)p;
        }
      }
    }

    // PV: O[32 q][64 v] += P[32][32] * V[32][64]
#pragma unroll
    for (int rt = 0; rt < 2; ++rt) {
      bf16x8v pa = *(bf16x8v*)&Psw[(rt * 16 + tx) * 32 + ((quad ^ h2) * 8)];
#pragma unroll
      for (int nt = 0; nt < 4; ++nt) {
        bf16x8v vb = *(bf16x8v*)&Vtw[(nt * 16 + tx) * 32 + ((quad ^ h2) * 8)];
        oacc[rt][nt] = MFMA16(pa, vb, oacc[rt][nt]);
      }
    }
  }

  // ---- cross-wave combine (private 8KB f32 regions, no atomics) ----
  __syncthreads();
  float* myO = (float*)(lds + w * 8192);  // 32 x 64 f32 (exactly 8KB)
  float* myL = Lsh + w * 32;
#pragma unroll
  for (int rt = 0; rt < 2; ++rt)
#pragma unroll
    for (int nt = 0; nt < 4; ++nt)
#pragma unroll
      for (int r = 0; r < 4; ++r)
        myO[(rt * 16 + quad * 4 + r) * 64 + nt * 16 + tx] = oacc[rt][nt][r];
#pragma unroll
  for (int rt = 0; rt < 2; ++rt)
#pragma unroll
    for (int r = 0; r < 4; ++r) {
      float v = lsum[rt][r];
#pragma unroll
      for (int m = 1; m < 16; m <<= 1) v += __shfl_xor(v, m, 64);
      if (tx == 0) myL[rt * 16 + quad * 4 + r] = v;
    }
  __syncthreads();

  // combined, normalized O -> vob (bf16, row-swizzled for A-frag reads)
#pragma unroll
  for (int p = 0; p < 4; ++p) {
    int e = tid + p * 512;  // 2048: 32 rows x 64 cols
    int row = e >> 6, col = e & 63;
    float s = 0.f, lt = 0.f;
#pragma unroll
    for (int wv = 0; wv < 8; ++wv) {
      s += ((const float*)(lds + wv * 8192))[e];
      lt += Lsh[wv * 32 + row];
    }
    vob[row * 64 + (((col >> 3) ^ (row & 7)) * 8) + (col & 7)] = (bf16)(s / lt);
  }
  __syncthreads();

  // ---- fused dense epilogue: out[32 x 512] = vob[32 x 64] @ drt^T ----
  bf16x8v av[2][2];
#pragma unroll
  for (int rt = 0; rt < 2; ++rt) {
    av[rt][0] = *(bf16x8v*)&vob[(rt * 16 + tx) * 64 + kc0];
    av[rt][1] = *(bf16x8v*)&vob[(rt * 16 + tx) * 64 + kc1];
  }

  float* OutS = (float*)lds;  // 32 x 260 f32 = 33280 B (aliases dead slots)
#pragma unroll
  for (int c = 0; c < 2; ++c) {  // two 256-col chunks
    if (c) __syncthreads();      // prior chunk's LDS reads done
#pragma unroll
    for (int i = 0; i < 2; ++i) {
      const int ct = c * 16 + w * 2 + i;  // global 16-col tile
      bf16x8v bd0 =
          *(const bf16x8v*)&drt[(size_t)(ct * 16 + tx) * 64 + quad * 8];
      bf16x8v bd1 =
          *(const bf16x8v*)&drt[(size_t)(ct * 16 + tx) * 64 + 32 + quad * 8];
#pragma unroll
      for (int rt = 0; rt < 2; ++rt) {
        f32x4 z = (f32x4){0.f, 0.f, 0.f, 0.f};
        z = MFMA16(av[rt][0], bd0, z);
        z = MFMA16(av[rt][1], bd1, z);
#pragma unroll
        for (int r = 0; r < 4; ++r)
          OutS[(rt * 16 + quad * 4 + r) * 260 + (w * 2 + i) * 16 + tx] = z[r];
      }
    }
    __syncthreads();
    // coalesced full-row stores: 32 rows x 256 f32 = 1KB contiguous per row
#pragma unroll
    for (int p = 0; p < 4; ++p) {
      int e = tid + p * 512;  // 2048 float4
      int row = e >> 6, seg = e & 63;
      *(float4*)&out[(size_t)(b * kS + q0 + row) * kD + c * 256 + seg * 4] =
          *(float4*)&OutS[row * 260 + seg * 4];
    }
  }
}

extern "C" void kernel_launch(void* const* d_in, const int* in_sizes, int n_in,
                              void* d_out, int out_size, void* d_ws,
                              size_t ws_size, hipStream_t stream) {
  const float* x = (const float*)d_in[0];      // [8,2048,512]
  const float* w = (const float*)d_in[1];      // [3,512,64]
  const float* dense = (const float*)d_in[2];  // [512,512]
  float* out = (float*)d_out;                  // [8,2048,512] fp32

  bf16* wq = (bf16*)d_ws;                // 1,048,576 bf16
  bf16* wk = wq + (size_t)kRows * 64;    // 1,048,576
  bf16* wvt = wk + (size_t)kRows * 64;   // 1,048,576  [64][16384]
  bf16* wtg = wvt + (size_t)kRows * 64;  // 98,304     [3][64][512]
  bf16* drt = wtg + 98304;               // 32,768     [512][64]

  prep_kernel<<<512, 256, 0, stream>>>(w, dense, wtg, drt);
  proj_kernel<<<256, 256, 0, stream>>>(x, wtg, wq, wk, wvt);
  flash_kernel<<<512, 512, 0, stream>>>(wq, wk, wvt, drt, out);
}